// Round 6
// baseline (1458.429 us; speedup 1.0000x reference)
//
#include <hip/hip_runtime.h>
#include <hip/hip_bf16.h>

#define BS 64
#define SEQ 200
#define NSK 4096
#define DS 256
#define SM 64
#define NROWS (BS*SEQ)
#define LW_VG 46        // weight frags kept in VGPR per wave (of 64)
#define LW_LDS 18       // weight frags in LDS per wave
#define LSTM_LDS (147456 + 8192)   // 144KB weights + 8KB h

typedef __attribute__((ext_vector_type(8))) short bf16x8;
typedef __attribute__((ext_vector_type(4))) float f32x4;

__device__ __forceinline__ float sigf(float x){ return 1.0f/(1.0f+expf(-x)); }
__device__ __forceinline__ float fast_sig(float x){ return 1.0f/(1.0f+__expf(-x)); }
__device__ __forceinline__ float fast_tanh(float x){
  float t = __expf(-2.0f*fabsf(x));
  float r = (1.0f - t)/(1.0f + t);
  return copysignf(r, x);
}
__device__ __forceinline__ short f2bf(float x){
  unsigned int u = __float_as_uint(x);
  unsigned int r = (u + 0x7fffu + ((u >> 16) & 1u)) >> 16;
  return (short)r;
}
__device__ __forceinline__ float bf2f(unsigned short s){
  return __uint_as_float(((unsigned int)s) << 16);
}

// ---------------- Kernel A: gather k,v + attention softmax w ----------------
__global__ __launch_bounds__(256) void k_gather_attn(
    const int* __restrict__ q, const int* __restrict__ r,
    const float* __restrict__ k_emb, const float* __restrict__ x_emb,
    const float* __restrict__ Mk,
    float* __restrict__ X2, float* __restrict__ vbuf, float* __restrict__ wbuf)
{
  __shared__ float ks[4][DS];
  const int tid = threadIdx.x;
  const int wv = tid >> 6, ln = tid & 63;
  const int row = blockIdx.x * 4 + wv;
  const int b = row / SEQ, s = row % SEQ;
  const int qi = q[b*SEQ + s];
  const int ri = r[b*SEQ + s];
  const float4* kr = (const float4*)(k_emb + (size_t)qi * DS);
  const float4* vr = (const float4*)(x_emb + ((size_t)qi + (size_t)NSK * ri) * DS);
  float4 kv = kr[ln];
  float4 vv = vr[ln];
  ((float4*)(X2 + (size_t)row*512 + DS))[ln] = kv;
  ((float4*)(vbuf + (size_t)row*DS))[ln] = vv;
  *((float4*)&ks[wv][ln*4]) = kv;
  __syncthreads();
  const float4* mkr = (const float4*)(Mk + (size_t)ln * DS);
  float a0=0.f,a1=0.f,a2=0.f,a3=0.f;
  #pragma unroll 8
  for (int d4=0; d4<DS/4; d4++){
    float4 m4 = mkr[d4];
    float4 k4 = *((const float4*)&ks[wv][d4*4]);
    a0 += m4.x*k4.x; a1 += m4.y*k4.y; a2 += m4.z*k4.z; a3 += m4.w*k4.w;
  }
  float lg = (a0+a1)+(a2+a3);
  float mx = lg;
  #pragma unroll
  for (int off=32; off; off>>=1) mx = fmaxf(mx, __shfl_xor(mx, off));
  float ex = expf(lg - mx);
  float sm = ex;
  #pragma unroll
  for (int off=32; off; off>>=1) sm += __shfl_xor(sm, off);
  wbuf[(size_t)row*SM + ln] = ex / sm;
}

// ---------------- bf16 MFMA GEMM: C = act(A @ W^T + bias [+bias2]) ----------
// ABF: A is bf16 (else f32). OUT: 0 f32 linear, 1 bf16 linear, 2 bf16 gate-
// interleaved ([m][ (n&255)*4 + (n>>8) ], for the LSTM's gin layout).
template<int ACT, int ABF, int OUT>
__global__ __launch_bounds__(256) void k_gemm2(
    const void* __restrict__ A0, int lda0, int K0,
    const void* __restrict__ A1, int lda1, int K1,
    const float* __restrict__ W, const float* __restrict__ bias,
    const float* __restrict__ bias2,
    void* __restrict__ C, int N)
{
  const int K = K0 + K1;
  __shared__ __align__(16) char As[64*80];
  __shared__ __align__(16) char Bs[64*80];
  const int tid = threadIdx.x;
  const int l = tid & 63, w = tid >> 6;
  const int m0 = blockIdx.x * 64, n0 = blockIdx.y * 64;
  const int mh = w >> 1, nh = w & 1;
  const int srow = tid >> 2, sseg = tid & 3;

  f32x4 acc[2][2];
  #pragma unroll
  for (int i=0;i<2;i++)
    #pragma unroll
    for (int j=0;j<2;j++) acc[i][j] = (f32x4){0.f,0.f,0.f,0.f};

  for (int k0=0; k0<K; k0+=32){
    const int kk = k0 + sseg*8;
    bf16x8 av;
    if (ABF){
      const ushort* ap = (kk < K0) ? (const ushort*)A0 + (size_t)(m0+srow)*lda0 + kk
                                   : (const ushort*)A1 + (size_t)(m0+srow)*lda1 + (kk-K0);
      av = *(const bf16x8*)ap;
    } else {
      const float* ap = (kk < K0) ? (const float*)A0 + (size_t)(m0+srow)*lda0 + kk
                                  : (const float*)A1 + (size_t)(m0+srow)*lda1 + (kk-K0);
      float4 a1 = *(const float4*)ap;
      float4 a2 = *(const float4*)(ap+4);
      av[0]=f2bf(a1.x); av[1]=f2bf(a1.y); av[2]=f2bf(a1.z); av[3]=f2bf(a1.w);
      av[4]=f2bf(a2.x); av[5]=f2bf(a2.y); av[6]=f2bf(a2.z); av[7]=f2bf(a2.w);
    }
    *(bf16x8*)(As + srow*80 + ((sseg ^ (srow&3))*16)) = av;
    const float* wp = W + (size_t)(n0+srow)*K + kk;
    float4 b1 = *(const float4*)wp;
    float4 b2 = *(const float4*)(wp+4);
    bf16x8 bv;
    bv[0]=f2bf(b1.x); bv[1]=f2bf(b1.y); bv[2]=f2bf(b1.z); bv[3]=f2bf(b1.w);
    bv[4]=f2bf(b2.x); bv[5]=f2bf(b2.y); bv[6]=f2bf(b2.z); bv[7]=f2bf(b2.w);
    *(bf16x8*)(Bs + srow*80 + ((sseg ^ (srow&3))*16)) = bv;
    __syncthreads();
    bf16x8 af[2], bf[2];
    #pragma unroll
    for (int mi=0; mi<2; mi++){
      const int row = mh*32 + mi*16 + (l&15);
      af[mi] = *(const bf16x8*)(As + row*80 + (((l>>4) ^ (row&3))*16));
    }
    #pragma unroll
    for (int ni=0; ni<2; ni++){
      const int row = nh*32 + ni*16 + (l&15);
      bf[ni] = *(const bf16x8*)(Bs + row*80 + (((l>>4) ^ (row&3))*16));
    }
    #pragma unroll
    for (int mi=0; mi<2; mi++)
      #pragma unroll
      for (int ni=0; ni<2; ni++)
        acc[mi][ni] = __builtin_amdgcn_mfma_f32_16x16x32_bf16(af[mi], bf[ni], acc[mi][ni], 0,0,0);
    __syncthreads();
  }
  #pragma unroll
  for (int mi=0; mi<2; mi++){
    #pragma unroll
    for (int ni=0; ni<2; ni++){
      const int n = n0 + nh*32 + ni*16 + (l&15);
      float bsum = bias[n] + (bias2 ? bias2[n] : 0.f);
      #pragma unroll
      for (int j=0;j<4;j++){
        const int m = m0 + mh*32 + mi*16 + (l>>4)*4 + j;
        float v = acc[mi][ni][j] + bsum;
        if (ACT==1) v = sigf(v);
        else if (ACT==2) v = tanhf(v);
        if (OUT==0)      ((float*)C)[(size_t)m*N + n] = v;
        else if (OUT==1) ((ushort*)C)[(size_t)m*N + n] = (ushort)f2bf(v);
        else             ((ushort*)C)[(size_t)m*N + ((n&255)*4 + (n>>8))] = (ushort)f2bf(v);
      }
    }
  }
}

// ---------------- fused erase/add GEMM (shared A = webuf bf16) --------------
__global__ __launch_bounds__(256) void k_gemm_ea(
    const ushort* __restrict__ A, const float* __restrict__ W_e,
    const float* __restrict__ b_e, const float* __restrict__ W_add,
    const float* __restrict__ b_add,
    float* __restrict__ ebuf, float* __restrict__ abuf)
{
  __shared__ __align__(16) char As[64*80];
  __shared__ __align__(16) char Bse[64*80];
  __shared__ __align__(16) char Bsa[64*80];
  const int tid = threadIdx.x;
  const int l = tid & 63, w = tid >> 6;
  const int m0 = blockIdx.x * 64, n0 = blockIdx.y * 64;
  const int mh = w >> 1, nh = w & 1;
  const int srow = tid >> 2, sseg = tid & 3;

  f32x4 acce[2][2], acca[2][2];
  #pragma unroll
  for (int i=0;i<2;i++)
    #pragma unroll
    for (int j=0;j<2;j++){ acce[i][j]=(f32x4){0.f,0.f,0.f,0.f}; acca[i][j]=(f32x4){0.f,0.f,0.f,0.f}; }

  for (int k0=0; k0<DS; k0+=32){
    const int kk = k0 + sseg*8;
    bf16x8 av = *(const bf16x8*)(A + (size_t)(m0+srow)*DS + kk);
    *(bf16x8*)(As + srow*80 + ((sseg ^ (srow&3))*16)) = av;
    {
      const float* wp = W_e + (size_t)(n0+srow)*DS + kk;
      float4 b1 = *(const float4*)wp; float4 b2 = *(const float4*)(wp+4);
      bf16x8 bv;
      bv[0]=f2bf(b1.x); bv[1]=f2bf(b1.y); bv[2]=f2bf(b1.z); bv[3]=f2bf(b1.w);
      bv[4]=f2bf(b2.x); bv[5]=f2bf(b2.y); bv[6]=f2bf(b2.z); bv[7]=f2bf(b2.w);
      *(bf16x8*)(Bse + srow*80 + ((sseg ^ (srow&3))*16)) = bv;
    }
    {
      const float* wp = W_add + (size_t)(n0+srow)*DS + kk;
      float4 b1 = *(const float4*)wp; float4 b2 = *(const float4*)(wp+4);
      bf16x8 bv;
      bv[0]=f2bf(b1.x); bv[1]=f2bf(b1.y); bv[2]=f2bf(b1.z); bv[3]=f2bf(b1.w);
      bv[4]=f2bf(b2.x); bv[5]=f2bf(b2.y); bv[6]=f2bf(b2.z); bv[7]=f2bf(b2.w);
      *(bf16x8*)(Bsa + srow*80 + ((sseg ^ (srow&3))*16)) = bv;
    }
    __syncthreads();
    bf16x8 af[2], bfe[2], bfa[2];
    #pragma unroll
    for (int mi=0; mi<2; mi++){
      const int row = mh*32 + mi*16 + (l&15);
      af[mi] = *(const bf16x8*)(As + row*80 + (((l>>4) ^ (row&3))*16));
    }
    #pragma unroll
    for (int ni=0; ni<2; ni++){
      const int row = nh*32 + ni*16 + (l&15);
      bfe[ni] = *(const bf16x8*)(Bse + row*80 + (((l>>4) ^ (row&3))*16));
      bfa[ni] = *(const bf16x8*)(Bsa + row*80 + (((l>>4) ^ (row&3))*16));
    }
    #pragma unroll
    for (int mi=0; mi<2; mi++)
      #pragma unroll
      for (int ni=0; ni<2; ni++){
        acce[mi][ni] = __builtin_amdgcn_mfma_f32_16x16x32_bf16(af[mi], bfe[ni], acce[mi][ni], 0,0,0);
        acca[mi][ni] = __builtin_amdgcn_mfma_f32_16x16x32_bf16(af[mi], bfa[ni], acca[mi][ni], 0,0,0);
      }
    __syncthreads();
  }
  #pragma unroll
  for (int mi=0; mi<2; mi++){
    #pragma unroll
    for (int ni=0; ni<2; ni++){
      const int n = n0 + nh*32 + ni*16 + (l&15);
      const float be = b_e[n], ba = b_add[n];
      #pragma unroll
      for (int j=0;j<4;j++){
        const int m = m0 + mh*32 + mi*16 + (l>>4)*4 + j;
        ebuf[(size_t)m*DS + n] = sigf(acce[mi][ni][j] + be);
        abuf[(size_t)m*DS + n] = tanhf(acca[mi][ni][j] + ba);
      }
    }
  }
}

// ---------------- Memory scan (sequential over t) ---------------------------
__global__ __launch_bounds__(256) void k_scan(
    const float* __restrict__ wbuf, const float* __restrict__ ebuf,
    const float* __restrict__ abuf, const float* __restrict__ Mv0,
    float* __restrict__ X2)
{
  const int b = blockIdx.x;
  const int d = threadIdx.x;
  __shared__ float ws[SM];
  float mem[SM];
  #pragma unroll
  for (int m=0;m<SM;m++) mem[m] = Mv0[m*DS + d];
  for (int t=0;t<SEQ;t++){
    const size_t row = (size_t)b*SEQ + t;
    if (d < SM) ws[d] = wbuf[row*SM + d];
    const float e = ebuf[row*DS + d];
    const float a = abuf[row*DS + d];
    __syncthreads();
    float r0=0.f,r1=0.f,r2=0.f,r3=0.f;
    #pragma unroll
    for (int m=0;m<SM;m+=4){
      float w0=ws[m], w1=ws[m+1], w2=ws[m+2], w3=ws[m+3];
      r0 += w0*mem[m];   mem[m]   += w0*fmaf(-e, mem[m],   a);
      r1 += w1*mem[m+1]; mem[m+1] += w1*fmaf(-e, mem[m+1], a);
      r2 += w2*mem[m+2]; mem[m+2] += w2*fmaf(-e, mem[m+2], a);
      r3 += w3*mem[m+3]; mem[m+3] += w3*fmaf(-e, mem[m+3], a);
    }
    X2[row*512 + d] = (r0+r1)+(r2+r3);
    __syncthreads();
  }
}

// ---------------- Zero-communication LSTM ------------------------------------
// 4 blocks x 512 threads; block g owns batches [16g,16g+16) and holds the FULL
// W_hh as bf16 MFMA B-fragments: 46/64 per-wave frags in VGPR, 18/64 in LDS
// (lane-private slots). h(t-1) staged in 8KB swizzled LDS. No inter-block
// communication at all. Two half-passes per step keep acc at 16 VGPRs.
__global__ __launch_bounds__(512, 2) void k_lstm_nc(
    const ushort* __restrict__ gin2, const float* __restrict__ W_hh,
    const float* __restrict__ hx, const float* __restrict__ cx,
    short* __restrict__ hhist)
{
  extern __shared__ char L[];
  char* wlds = L;                 // 144KB: [(w*18+slot)*1024 + l*16]
  char* hsm  = L + 147456;        // 8KB: 16 rows x 512B, XOR-swizzled

  const int g = blockIdx.x;
  const int tid = threadIdx.x;
  const int l = tid & 63, w = tid >> 6;

  // ---- setup: load W_hh as fragments ----
  // frag f = (gt*2+half)*8 + kt; lane l holds W[G][k],
  // G = gt*256 + w*32 + half*16 + (l&15), k = kt*32 + (l>>4)*8 + jj
  bf16x8 wv[LW_VG];
  #pragma unroll
  for (int nt=0; nt<8; nt++){
    const int gt = nt >> 1, half = nt & 1;
    const int G = gt*256 + w*32 + half*16 + (l & 15);
    const float* wrow = W_hh + (size_t)G*256;
    #pragma unroll
    for (int kt=0; kt<8; kt++){
      const int f = nt*8 + kt;
      const int k0 = kt*32 + (l>>4)*8;
      float4 wa = *(const float4*)(wrow + k0);
      float4 wb = *(const float4*)(wrow + k0 + 4);
      bf16x8 fr;
      fr[0]=f2bf(wa.x); fr[1]=f2bf(wa.y); fr[2]=f2bf(wa.z); fr[3]=f2bf(wa.w);
      fr[4]=f2bf(wb.x); fr[5]=f2bf(wb.y); fr[6]=f2bf(wb.z); fr[7]=f2bf(wb.w);
      if (f < LW_VG) wv[f] = fr;
      else *(bf16x8*)(wlds + ((w*LW_LDS + (f - LW_VG)) << 10) + l*16) = fr;
    }
  }

  // ---- c init: lane owns (b,d) for half 0..1, j 0..3 ----
  float c_[8];
  #pragma unroll
  for (int half=0; half<2; half++){
    const float c0 = cx[w*32 + half*16 + (l & 15)];
    #pragma unroll
    for (int j=0;j<4;j++) c_[half*4+j] = c0;
  }

  // ---- stage hx into hsm ----
  if (tid < 256){
    const int row = tid >> 4, seg = tid & 15;
    #pragma unroll
    for (int u=0; u<2; u++){
      const int kb = seg*32 + u*16;
      const int d0 = kb >> 1;
      float4 ha = *(const float4*)(hx + d0);
      float4 hb = *(const float4*)(hx + d0 + 4);
      bf16x8 v;
      v[0]=f2bf(ha.x); v[1]=f2bf(ha.y); v[2]=f2bf(ha.z); v[3]=f2bf(ha.w);
      v[4]=f2bf(hb.x); v[5]=f2bf(hb.y); v[6]=f2bf(hb.z); v[7]=f2bf(hb.w);
      *(bf16x8*)(hsm + row*512 + (kb ^ ((row&7)<<4))) = v;
    }
  }
  __syncthreads();

  for (int t=0; t<SEQ; t++){
    ushort hh[8];
    #pragma unroll
    for (int half=0; half<2; half++){
      // issue gin loads for this half (hidden under MFMA)
      unsigned long long gld[4];
      #pragma unroll
      for (int j=0;j<4;j++){
        const int b = g*16 + (l>>4)*4 + j;
        const int d = w*32 + half*16 + (l & 15);
        gld[j] = *(const unsigned long long*)
            ((const char*)gin2 + ((size_t)(b*SEQ + t)*1024 + d*4)*2);
      }
      // MFMA over all K for the 4 gates of this half
      f32x4 acc[4];
      #pragma unroll
      for (int gt=0; gt<4; gt++) acc[gt] = (f32x4){0.f,0.f,0.f,0.f};
      const int r0 = l & 15;
      #pragma unroll
      for (int kt=0; kt<8; kt++){
        const int kbyte = kt*64 + (l>>4)*16;
        bf16x8 a = *(const bf16x8*)(hsm + r0*512 + (kbyte ^ ((r0&7)<<4)));
        #pragma unroll
        for (int gt=0; gt<4; gt++){
          const int f = (gt*2 + half)*8 + kt;
          bf16x8 bfr;
          if (f < LW_VG) bfr = wv[f];
          else bfr = *(const bf16x8*)(wlds + ((w*LW_LDS + (f - LW_VG)) << 10) + l*16);
          acc[gt] = __builtin_amdgcn_mfma_f32_16x16x32_bf16(a, bfr, acc[gt], 0,0,0);
        }
      }
      // gates
      #pragma unroll
      for (int j=0;j<4;j++){
        const int b = g*16 + (l>>4)*4 + j;
        const int d = w*32 + half*16 + (l & 15);
        const unsigned long long gv = gld[j];
        float iv = acc[0][j] + bf2f((unsigned short)(gv       & 0xffffu));
        float fv = acc[1][j] + bf2f((unsigned short)((gv>>16) & 0xffffu));
        float gg = acc[2][j] + bf2f((unsigned short)((gv>>32) & 0xffffu));
        float ov = acc[3][j] + bf2f((unsigned short)((gv>>48) & 0xffffu));
        float cc = fast_sig(fv)*c_[half*4+j] + fast_sig(iv)*fast_tanh(gg);
        c_[half*4+j] = cc;
        float h = fast_sig(ov)*fast_tanh(cc);
        ushort hb = (ushort)f2bf(h);
        hh[half*4+j] = hb;
        hhist[((size_t)(b*SEQ + t))*256 + d] = (short)hb;
      }
    }
    __syncthreads();   // all reads of h(t-1) complete
    #pragma unroll
    for (int half=0; half<2; half++)
      #pragma unroll
      for (int j=0;j<4;j++){
        const int b = (l>>4)*4 + j;
        const int d = w*32 + half*16 + (l & 15);
        *(short*)(hsm + b*512 + ((d*2) ^ ((b&7)<<4))) = (short)hh[half*4+j];
      }
    __syncthreads();   // h(t) staged
  }
}

// ---------------- p output: sigmoid(h . W_p + b_p) --------------------------
__global__ __launch_bounds__(256) void k_pout(
    const short* __restrict__ hhist, const float* __restrict__ W_p,
    const float* __restrict__ b_p, float* __restrict__ out)
{
  const int tid = threadIdx.x;
  const int row = blockIdx.x*4 + (tid>>6);
  const int ln = tid & 63;
  ushort4 hv = ((const ushort4*)(hhist + (size_t)row*256))[ln];
  float4 wp = ((const float4*)W_p)[ln];
  float s = bf2f(hv.x)*wp.x + bf2f(hv.y)*wp.y + bf2f(hv.z)*wp.z + bf2f(hv.w)*wp.w;
  #pragma unroll
  for (int off=32; off; off>>=1) s += __shfl_xor(s, off);
  if (ln == 0) out[row] = sigf(s + b_p[0]);
}

extern "C" void kernel_launch(void* const* d_in, const int* in_sizes, int n_in,
                              void* d_out, int out_size, void* d_ws, size_t ws_size,
                              hipStream_t stream)
{
  const int*   q     = (const int*)d_in[0];
  const int*   r     = (const int*)d_in[1];
  const float* k_emb = (const float*)d_in[2];
  const float* x_emb = (const float*)d_in[3];
  const float* Mk    = (const float*)d_in[4];
  const float* Mv0   = (const float*)d_in[5];
  const float* W_a   = (const float*)d_in[6];
  const float* b_a   = (const float*)d_in[7];
  const float* W_e   = (const float*)d_in[8];
  const float* b_e   = (const float*)d_in[9];
  const float* W_add = (const float*)d_in[10];
  const float* b_add = (const float*)d_in[11];
  const float* W_f   = (const float*)d_in[12];
  const float* b_f   = (const float*)d_in[13];
  const float* hx    = (const float*)d_in[14];
  const float* cx    = (const float*)d_in[15];
  const float* W_ih  = (const float*)d_in[16];
  const float* b_ih  = (const float*)d_in[17];
  const float* W_hh  = (const float*)d_in[18];
  const float* b_hh  = (const float*)d_in[19];
  const float* W_p   = (const float*)d_in[20];
  const float* b_p   = (const float*)d_in[21];
  float* out = (float*)d_out;

  // byte-offset workspace layout
  char* base = (char*)d_ws;
  float*  vbuf  = (float*)(base);                          // 13.1MB
  ushort* webuf = (ushort*)(base + 13107200);              // 6.55MB
  float*  ebuf  = (float*)(base + 19660800);               // 13.1MB
  float*  abuf  = (float*)(base + 32768000);               // 13.1MB
  float*  X2    = (float*)(base + 45875200);               // 26.2MB [reads|k]
  float*  wbuf  = (float*)(base + 72089600);               // 3.3MB
  ushort* fbuf  = (ushort*)(base + 75366400);              // 6.55MB
  ushort* gin2  = (ushort*)(base);                         // 26.2MB overlay (vbuf..ebuf dead)
  short*  hhist = (short*)fbuf;                            // overlay (fbuf dead post-gin)

  k_gather_attn<<<NROWS/4, 256, 0, stream>>>(q, r, k_emb, x_emb, Mk, X2, vbuf, wbuf);
  // we = [k|v] @ W_a^T + b_a  -> bf16
  k_gemm2<0,0,1><<<dim3(NROWS/64, 4), 256, 0, stream>>>(X2+DS, 512, DS, vbuf, DS, DS, W_a, b_a, nullptr, webuf, DS);
  // erase/add fused (A = webuf bf16)
  k_gemm_ea<<<dim3(NROWS/64, 4), 256, 0, stream>>>(webuf, W_e, b_e, W_add, b_add, ebuf, abuf);
  // memory scan -> reads into X2[:,0:256]
  k_scan<<<BS, DS, 0, stream>>>(wbuf, ebuf, abuf, Mv0, X2);
  // f = tanh([reads|k] @ W_f^T + b_f) -> bf16
  k_gemm2<2,0,1><<<dim3(NROWS/64, 4), 256, 0, stream>>>(X2, 512, DS, X2+DS, 512, DS, W_f, b_f, nullptr, fbuf, DS);
  // gin = f @ W_ih^T + (b_ih + b_hh) -> bf16 gate-interleaved
  k_gemm2<0,1,2><<<dim3(NROWS/64, 16), 256, 0, stream>>>(fbuf, DS, DS, fbuf, DS, 0, W_ih, b_ih, b_hh, gin2, 1024);
  // zero-comm LSTM
  hipFuncSetAttribute((const void*)k_lstm_nc,
                      hipFuncAttributeMaxDynamicSharedMemorySize, LSTM_LDS);
  k_lstm_nc<<<4, 512, LSTM_LDS, stream>>>(gin2, W_hh, hx, cx, hhist);
  // p = sigmoid(h . W_p + b_p)
  k_pout<<<NROWS/4, 256, 0, stream>>>(hhist, W_p, b_p, out);
}

// Round 7
// 1438.684 us; speedup vs baseline: 1.0137x; 1.0137x over previous
//
#include <hip/hip_runtime.h>
#include <hip/hip_bf16.h>

#define BS 64
#define SEQ 200
#define NSK 4096
#define DS 256
#define SM 64
#define NROWS (BS*SEQ)
#define LW_VG 46        // weight frags kept in VGPR per wave (of 64)
#define LW_LDS 18       // weight frags in LDS per wave
#define LSTM_LDS (147456 + 8192)   // 144KB weights + 8KB h

typedef __attribute__((ext_vector_type(8))) short bf16x8;
typedef __attribute__((ext_vector_type(4))) float f32x4;

__device__ __forceinline__ float sigf(float x){ return 1.0f/(1.0f+expf(-x)); }
__device__ __forceinline__ float fast_sig(float x){ return 1.0f/(1.0f+__expf(-x)); }
__device__ __forceinline__ float fast_tanh(float x){
  float t = __expf(-2.0f*fabsf(x));
  float r = (1.0f - t)/(1.0f + t);
  return copysignf(r, x);
}
__device__ __forceinline__ short f2bf(float x){
  unsigned int u = __float_as_uint(x);
  unsigned int r = (u + 0x7fffu + ((u >> 16) & 1u)) >> 16;
  return (short)r;
}
__device__ __forceinline__ float bf2f(unsigned short s){
  return __uint_as_float(((unsigned int)s) << 16);
}

// ---------------- Kernel A: gather k,v + attention softmax w ----------------
__global__ __launch_bounds__(256) void k_gather_attn(
    const int* __restrict__ q, const int* __restrict__ r,
    const float* __restrict__ k_emb, const float* __restrict__ x_emb,
    const float* __restrict__ Mk,
    float* __restrict__ X2, float* __restrict__ vbuf, float* __restrict__ wbuf)
{
  __shared__ float ks[4][DS];
  const int tid = threadIdx.x;
  const int wv = tid >> 6, ln = tid & 63;
  const int row = blockIdx.x * 4 + wv;
  const int b = row / SEQ, s = row % SEQ;
  const int qi = q[b*SEQ + s];
  const int ri = r[b*SEQ + s];
  const float4* kr = (const float4*)(k_emb + (size_t)qi * DS);
  const float4* vr = (const float4*)(x_emb + ((size_t)qi + (size_t)NSK * ri) * DS);
  float4 kv = kr[ln];
  float4 vv = vr[ln];
  ((float4*)(X2 + (size_t)row*512 + DS))[ln] = kv;
  ((float4*)(vbuf + (size_t)row*DS))[ln] = vv;
  *((float4*)&ks[wv][ln*4]) = kv;
  __syncthreads();
  const float4* mkr = (const float4*)(Mk + (size_t)ln * DS);
  float a0=0.f,a1=0.f,a2=0.f,a3=0.f;
  #pragma unroll 8
  for (int d4=0; d4<DS/4; d4++){
    float4 m4 = mkr[d4];
    float4 k4 = *((const float4*)&ks[wv][d4*4]);
    a0 += m4.x*k4.x; a1 += m4.y*k4.y; a2 += m4.z*k4.z; a3 += m4.w*k4.w;
  }
  float lg = (a0+a1)+(a2+a3);
  float mx = lg;
  #pragma unroll
  for (int off=32; off; off>>=1) mx = fmaxf(mx, __shfl_xor(mx, off));
  float ex = expf(lg - mx);
  float sm = ex;
  #pragma unroll
  for (int off=32; off; off>>=1) sm += __shfl_xor(sm, off);
  wbuf[(size_t)row*SM + ln] = ex / sm;
}

// ---------------- bf16 MFMA GEMM: C = act(A @ W^T + bias [+bias2]) ----------
// ABF: A is bf16 (else f32). OUT: 0 f32 linear, 1 bf16 linear, 2 bf16 gate-
// interleaved ([m][ (n&255)*4 + (n>>8) ], for the LSTM's gin layout).
template<int ACT, int ABF, int OUT>
__global__ __launch_bounds__(256) void k_gemm2(
    const void* __restrict__ A0, int lda0, int K0,
    const void* __restrict__ A1, int lda1, int K1,
    const float* __restrict__ W, const float* __restrict__ bias,
    const float* __restrict__ bias2,
    void* __restrict__ C, int N)
{
  const int K = K0 + K1;
  __shared__ __align__(16) char As[64*80];
  __shared__ __align__(16) char Bs[64*80];
  const int tid = threadIdx.x;
  const int l = tid & 63, w = tid >> 6;
  const int m0 = blockIdx.x * 64, n0 = blockIdx.y * 64;
  const int mh = w >> 1, nh = w & 1;
  const int srow = tid >> 2, sseg = tid & 3;

  f32x4 acc[2][2];
  #pragma unroll
  for (int i=0;i<2;i++)
    #pragma unroll
    for (int j=0;j<2;j++) acc[i][j] = (f32x4){0.f,0.f,0.f,0.f};

  for (int k0=0; k0<K; k0+=32){
    const int kk = k0 + sseg*8;
    bf16x8 av;
    if (ABF){
      const ushort* ap = (kk < K0) ? (const ushort*)A0 + (size_t)(m0+srow)*lda0 + kk
                                   : (const ushort*)A1 + (size_t)(m0+srow)*lda1 + (kk-K0);
      av = *(const bf16x8*)ap;
    } else {
      const float* ap = (kk < K0) ? (const float*)A0 + (size_t)(m0+srow)*lda0 + kk
                                  : (const float*)A1 + (size_t)(m0+srow)*lda1 + (kk-K0);
      float4 a1 = *(const float4*)ap;
      float4 a2 = *(const float4*)(ap+4);
      av[0]=f2bf(a1.x); av[1]=f2bf(a1.y); av[2]=f2bf(a1.z); av[3]=f2bf(a1.w);
      av[4]=f2bf(a2.x); av[5]=f2bf(a2.y); av[6]=f2bf(a2.z); av[7]=f2bf(a2.w);
    }
    *(bf16x8*)(As + srow*80 + ((sseg ^ (srow&3))*16)) = av;
    const float* wp = W + (size_t)(n0+srow)*K + kk;
    float4 b1 = *(const float4*)wp;
    float4 b2 = *(const float4*)(wp+4);
    bf16x8 bv;
    bv[0]=f2bf(b1.x); bv[1]=f2bf(b1.y); bv[2]=f2bf(b1.z); bv[3]=f2bf(b1.w);
    bv[4]=f2bf(b2.x); bv[5]=f2bf(b2.y); bv[6]=f2bf(b2.z); bv[7]=f2bf(b2.w);
    *(bf16x8*)(Bs + srow*80 + ((sseg ^ (srow&3))*16)) = bv;
    __syncthreads();
    bf16x8 af[2], bf[2];
    #pragma unroll
    for (int mi=0; mi<2; mi++){
      const int row = mh*32 + mi*16 + (l&15);
      af[mi] = *(const bf16x8*)(As + row*80 + (((l>>4) ^ (row&3))*16));
    }
    #pragma unroll
    for (int ni=0; ni<2; ni++){
      const int row = nh*32 + ni*16 + (l&15);
      bf[ni] = *(const bf16x8*)(Bs + row*80 + (((l>>4) ^ (row&3))*16));
    }
    #pragma unroll
    for (int mi=0; mi<2; mi++)
      #pragma unroll
      for (int ni=0; ni<2; ni++)
        acc[mi][ni] = __builtin_amdgcn_mfma_f32_16x16x32_bf16(af[mi], bf[ni], acc[mi][ni], 0,0,0);
    __syncthreads();
  }
  #pragma unroll
  for (int mi=0; mi<2; mi++){
    #pragma unroll
    for (int ni=0; ni<2; ni++){
      const int n = n0 + nh*32 + ni*16 + (l&15);
      float bsum = bias[n] + (bias2 ? bias2[n] : 0.f);
      #pragma unroll
      for (int j=0;j<4;j++){
        const int m = m0 + mh*32 + mi*16 + (l>>4)*4 + j;
        float v = acc[mi][ni][j] + bsum;
        if (ACT==1) v = sigf(v);
        else if (ACT==2) v = tanhf(v);
        if (OUT==0)      ((float*)C)[(size_t)m*N + n] = v;
        else if (OUT==1) ((ushort*)C)[(size_t)m*N + n] = (ushort)f2bf(v);
        else             ((ushort*)C)[(size_t)m*N + ((n&255)*4 + (n>>8))] = (ushort)f2bf(v);
      }
    }
  }
}

// ---------------- fused erase/add GEMM (shared A = webuf bf16) --------------
__global__ __launch_bounds__(256) void k_gemm_ea(
    const ushort* __restrict__ A, const float* __restrict__ W_e,
    const float* __restrict__ b_e, const float* __restrict__ W_add,
    const float* __restrict__ b_add,
    float* __restrict__ ebuf, float* __restrict__ abuf)
{
  __shared__ __align__(16) char As[64*80];
  __shared__ __align__(16) char Bse[64*80];
  __shared__ __align__(16) char Bsa[64*80];
  const int tid = threadIdx.x;
  const int l = tid & 63, w = tid >> 6;
  const int m0 = blockIdx.x * 64, n0 = blockIdx.y * 64;
  const int mh = w >> 1, nh = w & 1;
  const int srow = tid >> 2, sseg = tid & 3;

  f32x4 acce[2][2], acca[2][2];
  #pragma unroll
  for (int i=0;i<2;i++)
    #pragma unroll
    for (int j=0;j<2;j++){ acce[i][j]=(f32x4){0.f,0.f,0.f,0.f}; acca[i][j]=(f32x4){0.f,0.f,0.f,0.f}; }

  for (int k0=0; k0<DS; k0+=32){
    const int kk = k0 + sseg*8;
    bf16x8 av = *(const bf16x8*)(A + (size_t)(m0+srow)*DS + kk);
    *(bf16x8*)(As + srow*80 + ((sseg ^ (srow&3))*16)) = av;
    {
      const float* wp = W_e + (size_t)(n0+srow)*DS + kk;
      float4 b1 = *(const float4*)wp; float4 b2 = *(const float4*)(wp+4);
      bf16x8 bv;
      bv[0]=f2bf(b1.x); bv[1]=f2bf(b1.y); bv[2]=f2bf(b1.z); bv[3]=f2bf(b1.w);
      bv[4]=f2bf(b2.x); bv[5]=f2bf(b2.y); bv[6]=f2bf(b2.z); bv[7]=f2bf(b2.w);
      *(bf16x8*)(Bse + srow*80 + ((sseg ^ (srow&3))*16)) = bv;
    }
    {
      const float* wp = W_add + (size_t)(n0+srow)*DS + kk;
      float4 b1 = *(const float4*)wp; float4 b2 = *(const float4*)(wp+4);
      bf16x8 bv;
      bv[0]=f2bf(b1.x); bv[1]=f2bf(b1.y); bv[2]=f2bf(b1.z); bv[3]=f2bf(b1.w);
      bv[4]=f2bf(b2.x); bv[5]=f2bf(b2.y); bv[6]=f2bf(b2.z); bv[7]=f2bf(b2.w);
      *(bf16x8*)(Bsa + srow*80 + ((sseg ^ (srow&3))*16)) = bv;
    }
    __syncthreads();
    bf16x8 af[2], bfe[2], bfa[2];
    #pragma unroll
    for (int mi=0; mi<2; mi++){
      const int row = mh*32 + mi*16 + (l&15);
      af[mi] = *(const bf16x8*)(As + row*80 + (((l>>4) ^ (row&3))*16));
    }
    #pragma unroll
    for (int ni=0; ni<2; ni++){
      const int row = nh*32 + ni*16 + (l&15);
      bfe[ni] = *(const bf16x8*)(Bse + row*80 + (((l>>4) ^ (row&3))*16));
      bfa[ni] = *(const bf16x8*)(Bsa + row*80 + (((l>>4) ^ (row&3))*16));
    }
    #pragma unroll
    for (int mi=0; mi<2; mi++)
      #pragma unroll
      for (int ni=0; ni<2; ni++){
        acce[mi][ni] = __builtin_amdgcn_mfma_f32_16x16x32_bf16(af[mi], bfe[ni], acce[mi][ni], 0,0,0);
        acca[mi][ni] = __builtin_amdgcn_mfma_f32_16x16x32_bf16(af[mi], bfa[ni], acca[mi][ni], 0,0,0);
      }
    __syncthreads();
  }
  #pragma unroll
  for (int mi=0; mi<2; mi++){
    #pragma unroll
    for (int ni=0; ni<2; ni++){
      const int n = n0 + nh*32 + ni*16 + (l&15);
      const float be = b_e[n], ba = b_add[n];
      #pragma unroll
      for (int j=0;j<4;j++){
        const int m = m0 + mh*32 + mi*16 + (l>>4)*4 + j;
        ebuf[(size_t)m*DS + n] = sigf(acce[mi][ni][j] + be);
        abuf[(size_t)m*DS + n] = tanhf(acca[mi][ni][j] + ba);
      }
    }
  }
}

// ---------------- Memory scan (sequential over t) ---------------------------
__global__ __launch_bounds__(256) void k_scan(
    const float* __restrict__ wbuf, const float* __restrict__ ebuf,
    const float* __restrict__ abuf, const float* __restrict__ Mv0,
    float* __restrict__ X2)
{
  const int b = blockIdx.x;
  const int d = threadIdx.x;
  __shared__ float ws[SM];
  float mem[SM];
  #pragma unroll
  for (int m=0;m<SM;m++) mem[m] = Mv0[m*DS + d];
  for (int t=0;t<SEQ;t++){
    const size_t row = (size_t)b*SEQ + t;
    if (d < SM) ws[d] = wbuf[row*SM + d];
    const float e = ebuf[row*DS + d];
    const float a = abuf[row*DS + d];
    __syncthreads();
    float r0=0.f,r1=0.f,r2=0.f,r3=0.f;
    #pragma unroll
    for (int m=0;m<SM;m+=4){
      float w0=ws[m], w1=ws[m+1], w2=ws[m+2], w3=ws[m+3];
      r0 += w0*mem[m];   mem[m]   += w0*fmaf(-e, mem[m],   a);
      r1 += w1*mem[m+1]; mem[m+1] += w1*fmaf(-e, mem[m+1], a);
      r2 += w2*mem[m+2]; mem[m+2] += w2*fmaf(-e, mem[m+2], a);
      r3 += w3*mem[m+3]; mem[m+3] += w3*fmaf(-e, mem[m+3], a);
    }
    X2[row*512 + d] = (r0+r1)+(r2+r3);
    __syncthreads();
  }
}

// ---------------- Zero-communication LSTM ------------------------------------
// 4 blocks x 512 threads; block g owns batches [16g,16g+16) and holds the FULL
// W_hh as bf16 MFMA B-fragments: 46/64 per-wave frags in VGPR, 18/64 in LDS.
// __launch_bounds__(512,1): 1 block/CU -> 2 waves/SIMD -> 256-VGPR budget; the
// previous (512,2) capped the allocator at 128 VGPRs and spilled wv[] (R6).
__global__ __launch_bounds__(512, 1) void k_lstm_nc(
    const ushort* __restrict__ gin2, const float* __restrict__ W_hh,
    const float* __restrict__ hx, const float* __restrict__ cx,
    short* __restrict__ hhist)
{
  extern __shared__ char L[];
  char* wlds = L;                 // 144KB: [(w*18+slot)*1024 + l*16]
  char* hsm  = L + 147456;        // 8KB: 16 rows x 512B, XOR-swizzled

  const int g = blockIdx.x;
  const int tid = threadIdx.x;
  const int l = tid & 63, w = tid >> 6;

  // ---- setup: load W_hh as fragments ----
  bf16x8 wv[LW_VG];
  #pragma unroll
  for (int nt=0; nt<8; nt++){
    const int gt = nt >> 1, half = nt & 1;
    const int G = gt*256 + w*32 + half*16 + (l & 15);
    const float* wrow = W_hh + (size_t)G*256;
    #pragma unroll
    for (int kt=0; kt<8; kt++){
      const int f = nt*8 + kt;
      const int k0 = kt*32 + (l>>4)*8;
      float4 wa = *(const float4*)(wrow + k0);
      float4 wb = *(const float4*)(wrow + k0 + 4);
      bf16x8 fr;
      fr[0]=f2bf(wa.x); fr[1]=f2bf(wa.y); fr[2]=f2bf(wa.z); fr[3]=f2bf(wa.w);
      fr[4]=f2bf(wb.x); fr[5]=f2bf(wb.y); fr[6]=f2bf(wb.z); fr[7]=f2bf(wb.w);
      if (f < LW_VG) wv[f] = fr;
      else *(bf16x8*)(wlds + ((w*LW_LDS + (f - LW_VG)) << 10) + l*16) = fr;
    }
  }

  // ---- c init: lane owns (b,d) for half 0..1, j 0..3 ----
  float c_[8];
  #pragma unroll
  for (int half=0; half<2; half++){
    const float c0 = cx[w*32 + half*16 + (l & 15)];
    #pragma unroll
    for (int j=0;j<4;j++) c_[half*4+j] = c0;
  }

  // ---- stage hx into hsm ----
  if (tid < 256){
    const int row = tid >> 4, seg = tid & 15;
    #pragma unroll
    for (int u=0; u<2; u++){
      const int kb = seg*32 + u*16;
      const int d0 = kb >> 1;
      float4 ha = *(const float4*)(hx + d0);
      float4 hb = *(const float4*)(hx + d0 + 4);
      bf16x8 v;
      v[0]=f2bf(ha.x); v[1]=f2bf(ha.y); v[2]=f2bf(ha.z); v[3]=f2bf(ha.w);
      v[4]=f2bf(hb.x); v[5]=f2bf(hb.y); v[6]=f2bf(hb.z); v[7]=f2bf(hb.w);
      *(bf16x8*)(hsm + row*512 + (kb ^ ((row&7)<<4))) = v;
    }
  }
  __syncthreads();

  // running pointers (per lane): batch b0 = g*16 + (l>>4)*4, dims d0/d1 per half
  const int b0 = g*16 + (l>>4)*4;
  const int d0 = w*32 + (l & 15);          // half 0 dim
  const char* gp = (const char*)gin2 + ((size_t)(b0*SEQ)*1024 + d0*4)*2;
  char* hp = (char*)hhist + ((size_t)(b0*SEQ)*256 + d0)*2;

  for (int t=0; t<SEQ; t++){
    ushort hh[8];
    #pragma unroll
    for (int half=0; half<2; half++){
      // issue gin loads for this half (hidden under MFMA)
      unsigned long long gld[4];
      #pragma unroll
      for (int j=0;j<4;j++)
        gld[j] = *(const unsigned long long*)(gp + (size_t)j*(SEQ*2048) + half*128);
      // MFMA over all K for the 4 gates of this half
      f32x4 acc[4];
      #pragma unroll
      for (int gt=0; gt<4; gt++) acc[gt] = (f32x4){0.f,0.f,0.f,0.f};
      const int r0 = l & 15;
      #pragma unroll
      for (int kt=0; kt<8; kt++){
        const int kbyte = kt*64 + (l>>4)*16;
        bf16x8 a = *(const bf16x8*)(hsm + r0*512 + (kbyte ^ ((r0&7)<<4)));
        #pragma unroll
        for (int gt=0; gt<4; gt++){
          const int f = (gt*2 + half)*8 + kt;
          bf16x8 bfr;
          if (f < LW_VG) bfr = wv[f];
          else bfr = *(const bf16x8*)(wlds + ((w*LW_LDS + (f - LW_VG)) << 10) + l*16);
          acc[gt] = __builtin_amdgcn_mfma_f32_16x16x32_bf16(a, bfr, acc[gt], 0,0,0);
        }
      }
      // gates
      #pragma unroll
      for (int j=0;j<4;j++){
        const unsigned long long gv = gld[j];
        float iv = acc[0][j] + bf2f((unsigned short)(gv       & 0xffffu));
        float fv = acc[1][j] + bf2f((unsigned short)((gv>>16) & 0xffffu));
        float gg = acc[2][j] + bf2f((unsigned short)((gv>>32) & 0xffffu));
        float ov = acc[3][j] + bf2f((unsigned short)((gv>>48) & 0xffffu));
        float cc = fast_sig(fv)*c_[half*4+j] + fast_sig(iv)*fast_tanh(gg);
        c_[half*4+j] = cc;
        float h = fast_sig(ov)*fast_tanh(cc);
        ushort hb = (ushort)f2bf(h);
        hh[half*4+j] = hb;
        *(short*)(hp + (size_t)j*(SEQ*512) + half*32) = (short)hb;
      }
    }
    gp += 2048;   // next t: +1024 ushorts
    hp += 512;    // next t: +256 shorts
    __syncthreads();   // all reads of h(t-1) complete
    #pragma unroll
    for (int half=0; half<2; half++)
      #pragma unroll
      for (int j=0;j<4;j++){
        const int b = (l>>4)*4 + j;
        const int d = w*32 + half*16 + (l & 15);
        *(short*)(hsm + b*512 + ((d*2) ^ ((b&7)<<4))) = (short)hh[half*4+j];
      }
    __syncthreads();   // h(t) staged
  }
}

// ---------------- p output: sigmoid(h . W_p + b_p) --------------------------
__global__ __launch_bounds__(256) void k_pout(
    const short* __restrict__ hhist, const float* __restrict__ W_p,
    const float* __restrict__ b_p, float* __restrict__ out)
{
  const int tid = threadIdx.x;
  const int row = blockIdx.x*4 + (tid>>6);
  const int ln = tid & 63;
  ushort4 hv = ((const ushort4*)(hhist + (size_t)row*256))[ln];
  float4 wp = ((const float4*)W_p)[ln];
  float s = bf2f(hv.x)*wp.x + bf2f(hv.y)*wp.y + bf2f(hv.z)*wp.z + bf2f(hv.w)*wp.w;
  #pragma unroll
  for (int off=32; off; off>>=1) s += __shfl_xor(s, off);
  if (ln == 0) out[row] = sigf(s + b_p[0]);
}

extern "C" void kernel_launch(void* const* d_in, const int* in_sizes, int n_in,
                              void* d_out, int out_size, void* d_ws, size_t ws_size,
                              hipStream_t stream)
{
  const int*   q     = (const int*)d_in[0];
  const int*   r     = (const int*)d_in[1];
  const float* k_emb = (const float*)d_in[2];
  const float* x_emb = (const float*)d_in[3];
  const float* Mk    = (const float*)d_in[4];
  const float* Mv0   = (const float*)d_in[5];
  const float* W_a   = (const float*)d_in[6];
  const float* b_a   = (const float*)d_in[7];
  const float* W_e   = (const float*)d_in[8];
  const float* b_e   = (const float*)d_in[9];
  const float* W_add = (const float*)d_in[10];
  const float* b_add = (const float*)d_in[11];
  const float* W_f   = (const float*)d_in[12];
  const float* b_f   = (const float*)d_in[13];
  const float* hx    = (const float*)d_in[14];
  const float* cx    = (const float*)d_in[15];
  const float* W_ih  = (const float*)d_in[16];
  const float* b_ih  = (const float*)d_in[17];
  const float* W_hh  = (const float*)d_in[18];
  const float* b_hh  = (const float*)d_in[19];
  const float* W_p   = (const float*)d_in[20];
  const float* b_p   = (const float*)d_in[21];
  float* out = (float*)d_out;

  // byte-offset workspace layout
  char* base = (char*)d_ws;
  float*  vbuf  = (float*)(base);                          // 13.1MB
  ushort* webuf = (ushort*)(base + 13107200);              // 6.55MB
  float*  ebuf  = (float*)(base + 19660800);               // 13.1MB
  float*  abuf  = (float*)(base + 32768000);               // 13.1MB
  float*  X2    = (float*)(base + 45875200);               // 26.2MB [reads|k]
  float*  wbuf  = (float*)(base + 72089600);               // 3.3MB
  ushort* fbuf  = (ushort*)(base + 75366400);              // 6.55MB
  ushort* gin2  = (ushort*)(base);                         // 26.2MB overlay (vbuf..ebuf dead)
  short*  hhist = (short*)fbuf;                            // overlay (fbuf dead post-gin)

  k_gather_attn<<<NROWS/4, 256, 0, stream>>>(q, r, k_emb, x_emb, Mk, X2, vbuf, wbuf);
  // we = [k|v] @ W_a^T + b_a  -> bf16
  k_gemm2<0,0,1><<<dim3(NROWS/64, 4), 256, 0, stream>>>(X2+DS, 512, DS, vbuf, DS, DS, W_a, b_a, nullptr, webuf, DS);
  // erase/add fused (A = webuf bf16)
  k_gemm_ea<<<dim3(NROWS/64, 4), 256, 0, stream>>>(webuf, W_e, b_e, W_add, b_add, ebuf, abuf);
  // memory scan -> reads into X2[:,0:256]
  k_scan<<<BS, DS, 0, stream>>>(wbuf, ebuf, abuf, Mv0, X2);
  // f = tanh([reads|k] @ W_f^T + b_f) -> bf16
  k_gemm2<2,0,1><<<dim3(NROWS/64, 4), 256, 0, stream>>>(X2, 512, DS, X2+DS, 512, DS, W_f, b_f, nullptr, fbuf, DS);
  // gin = f @ W_ih^T + (b_ih + b_hh) -> bf16 gate-interleaved
  k_gemm2<0,1,2><<<dim3(NROWS/64, 16), 256, 0, stream>>>(fbuf, DS, DS, fbuf, DS, 0, W_ih, b_ih, b_hh, gin2, 1024);
  // zero-comm LSTM
  hipFuncSetAttribute((const void*)k_lstm_nc,
                      hipFuncAttributeMaxDynamicSharedMemorySize, LSTM_LDS);
  k_lstm_nc<<<4, 512, LSTM_LDS, stream>>>(gin2, W_hh, hx, cx, hhist);
  // p = sigmoid(h . W_p + b_p)
  k_pout<<<NROWS/4, 256, 0, stream>>>(hhist, W_p, b_p, out);
}